// Round 4
// baseline (435.972 us; speedup 1.0000x reference)
//
#include <hip/hip_runtime.h>
#include <hip/hip_cooperative_groups.h>
#include <math.h>

namespace cg = cooperative_groups;

#define N_NODES 50000
#define N_EDGES 600000
#define F 128
#define NT 4
#define NKTG 20                // K tiles of 32 (640 total K over 5 planes)
#define NCT 8                  // out-col tiles of 16 (128/16)
#define N_SEG (NT * N_NODES)   // 200000
#define SCAN_BLK 196           // ceil(N_SEG / 1024)
#define GT (SCAN_BLK * 256)    // 50176 threads in cooperative grid
#define WELEM (NKTG * NCT * 64 * 8)  // 81920 fp16 elements per layer
#define PER_LAYER (NKTG * NCT * 64)  // 10240 weight fragments

typedef __attribute__((ext_vector_type(8))) _Float16 f16x8;
typedef __attribute__((ext_vector_type(4))) float f32x4;

__device__ __forceinline__ unsigned short f2h(float f) {
    _Float16 h = (_Float16)f;
    return __builtin_bit_cast(unsigned short, h);
}
__device__ __forceinline__ unsigned pack2h(float a, float b) {
    return (unsigned)f2h(a) | ((unsigned)f2h(b) << 16);
}
__device__ __forceinline__ unsigned short f2b(float f) {   // fp32 -> bf16 RNE
    unsigned u = __float_as_uint(f);
    return (unsigned short)((u + 0x7FFFu + ((u >> 16) & 1u)) >> 16);
}

// ================= cooperative prep + CSR kernel =================
// ph0: zero counts | build combined weights | cast x->fp16
// ph1: histogram  ph2: block scan  ph3: scan of block sums
// ph4: finalize offsets + cursor + sentinel  ph5: permute
__global__ __launch_bounds__(256) void csr_prep(
    const float* __restrict__ x,
    const float* __restrict__ Ws1, const float* __restrict__ Wn1, const float* __restrict__ b1,
    const float* __restrict__ Ws2, const float* __restrict__ Wn2, const float* __restrict__ b2,
    const int* __restrict__ srcA, const int* __restrict__ dstA, const int* __restrict__ typA,
    unsigned short* __restrict__ x16,
    unsigned short* __restrict__ Wh, unsigned short* __restrict__ Wl,
    float* __restrict__ bavg,
    int* __restrict__ counts, int* __restrict__ cursor, int* __restrict__ bsum,
    unsigned long long* __restrict__ perm64)
{
    cg::grid_group grid = cg::this_grid();
    __shared__ int sh[256];
    const int t = threadIdx.x;
    const int gtid = blockIdx.x * 256 + t;

    // ---- ph0: zero counts ----
    for (int i = gtid; i < N_SEG + 2; i += GT) counts[i] = 0;

    // ---- ph0: build weights (fp16 hi/lo, frag order) + bias ----
    for (int idx = gtid; idx < 2 * PER_LAYER + 2 * F; idx += GT) {
        if (idx < 2 * PER_LAYER) {
            int l = idx >= PER_LAYER;
            int rem = idx - l * PER_LAYER;
            int lane = rem & 63;
            int ct = (rem >> 6) & 7;
            int ktg = (rem >> 6) >> 3;
            const float* Wsl = l ? Ws2 : Ws1;
            const float* Wnl = l ? Wn2 : Wn1;
            unsigned short* oh = Wh + (size_t)l * WELEM + (size_t)rem * 8;
            unsigned short* ol = Wl + (size_t)l * WELEM + (size_t)rem * 8;
            int c = ct * 16 + (lane & 15);
            int kb = ktg * 32 + (lane >> 4) * 8;
#pragma unroll
            for (int j = 0; j < 8; ++j) {
                int k = kb + j;
                float v;
                if (k < F) {
                    v = 0.25f * (Wsl[(0 * F + k) * F + c] + Wsl[(1 * F + k) * F + c] +
                                 Wsl[(2 * F + k) * F + c] + Wsl[(3 * F + k) * F + c]);
                } else {
                    int tt = (k - F) >> 7;
                    int kk = (k - F) & (F - 1);
                    v = 0.25f * Wnl[((size_t)tt * F + kk) * F + c];
                }
                _Float16 hh = (_Float16)v;
                oh[j] = __builtin_bit_cast(unsigned short, hh);
                ol[j] = f2h(v - (float)hh);
            }
        } else {
            int k = idx - 2 * PER_LAYER;
            int l = k >> 7;
            int j = k & (F - 1);
            const float* bl = l ? b2 : b1;
            bavg[k] = 0.25f * (bl[j] + bl[F + j] + bl[2 * F + j] + bl[3 * F + j]);
        }
    }

    // ---- ph0: cast x -> fp16 ----
    for (int i = gtid; i < N_NODES * 64; i += GT) {
        float2 v = ((const float2*)x)[i];
        ((unsigned*)x16)[i] = pack2h(v.x, v.y);
    }

    grid.sync();

    // ---- ph1: histogram ----
    for (int e = gtid; e < N_EDGES; e += GT)
        atomicAdd(&counts[dstA[e] * NT + typA[e]], 1);

    grid.sync();

    // ---- ph2: per-block scan of 1024 counts -> exclusive-in-block + bsum ----
    {
        int base = blockIdx.x * 1024 + t * 4;
        int v[4];
        int tot = 0;
#pragma unroll
        for (int j = 0; j < 4; ++j) {
            int i = base + j;
            v[j] = (i < N_SEG) ? counts[i] : 0;
            tot += v[j];
        }
        sh[t] = tot;
        __syncthreads();
        for (int ofs = 1; ofs < 256; ofs <<= 1) {
            int add = (t >= ofs) ? sh[t - ofs] : 0;
            __syncthreads();
            sh[t] += add;
            __syncthreads();
        }
        int excl = (t > 0) ? sh[t - 1] : 0;
        if (t == 255) bsum[blockIdx.x] = sh[255];
#pragma unroll
        for (int j = 0; j < 4; ++j) {
            int i = base + j;
            if (i < N_SEG) counts[i] = excl;
            excl += v[j];
        }
    }

    grid.sync();

    // ---- ph3: scan of 196 block sums (block 0 only) ----
    if (blockIdx.x == 0) {
        sh[t] = (t < SCAN_BLK) ? bsum[t] : 0;
        __syncthreads();
        for (int ofs = 1; ofs < 256; ofs <<= 1) {
            int add = (t >= ofs) ? sh[t - ofs] : 0;
            __syncthreads();
            sh[t] += add;
            __syncthreads();
        }
        int excl = (t > 0) ? sh[t - 1] : 0;
        if (t < SCAN_BLK) bsum[t] = excl;
    }

    grid.sync();

    // ---- ph4: finalize offsets, copy cursor, sentinel ----
    for (int i = gtid; i < N_SEG; i += GT) {
        int v = counts[i] + bsum[i >> 10];
        counts[i] = v;
        cursor[i] = v;
    }
    if (gtid == 0) counts[N_SEG] = N_EDGES;

    grid.sync();

    // ---- ph5: permute (pre-scaled payload) ----
    for (int e = gtid; e < N_EDGES; e += GT) {
        int tt = typA[e];
        int seg = dstA[e] * NT + tt;
        int pos = atomicAdd(&cursor[seg], 1);
        float inv = 1.0f / fmaxf((float)(counts[seg + 1] - counts[seg]), 1.0f);
        unsigned offw = (unsigned)(srcA[e] * 320 + (tt + 1) * 64);  // dword offset
        perm64[pos] = ((unsigned long long)__float_as_uint(inv) << 32) | offw;
    }
}

// ---- dense transform: Z[N,640] bf16 = Hin[N,128] fp16 @ B (5 planes x 128) ----
__global__ __launch_bounds__(256) void gemm_z(
    const unsigned short* __restrict__ Hin,
    const unsigned short* __restrict__ Wh,
    const unsigned short* __restrict__ Wl,
    unsigned short* __restrict__ Z)
{
    __shared__ unsigned short AS[64][136];

    const int tid = threadIdx.x;
    const int lane = tid & 63;
    const int w = tid >> 6;
    const int quad = lane >> 4;
    const int l15 = lane & 15;
    const int nodeBase = blockIdx.x * 64;

    {
        int r = tid >> 2;
        int cb = (tid & 3) * 32;
        int n = nodeBase + r;
        int nc = n < N_NODES ? n : N_NODES - 1;
        const unsigned short* srcp = Hin + (size_t)nc * F + cb;
        *(uint4*)&AS[r][cb]      = *(const uint4*)(srcp);
        *(uint4*)&AS[r][cb + 8]  = *(const uint4*)(srcp + 8);
        *(uint4*)&AS[r][cb + 16] = *(const uint4*)(srcp + 16);
        *(uint4*)&AS[r][cb + 24] = *(const uint4*)(srcp + 24);
    }
    __syncthreads();

    const f16x8* BH = (const f16x8*)Wh;
    const f16x8* BL = (const f16x8*)Wl;

#pragma unroll 1
    for (int cp = 0; cp < 5; ++cp) {
        f32x4 acc[4][2];
#pragma unroll
        for (int rt = 0; rt < 4; ++rt)
#pragma unroll
            for (int ci = 0; ci < 2; ++ci)
                acc[rt][ci] = (f32x4){0.f, 0.f, 0.f, 0.f};

#pragma unroll
        for (int kt = 0; kt < 4; ++kt) {
            f16x8 bh[2], bl[2];
#pragma unroll
            for (int ci = 0; ci < 2; ++ci) {
                int fi = ((cp * 4 + kt) * NCT + (w * 2 + ci)) * 64 + lane;
                bh[ci] = BH[fi];
                bl[ci] = BL[fi];
            }
            f16x8 ah[4];
#pragma unroll
            for (int rt = 0; rt < 4; ++rt)
                ah[rt] = *(const f16x8*)&AS[rt * 16 + l15][kt * 32 + quad * 8];
#pragma unroll
            for (int rt = 0; rt < 4; ++rt)
#pragma unroll
                for (int ci = 0; ci < 2; ++ci) {
                    acc[rt][ci] = __builtin_amdgcn_mfma_f32_16x16x32_f16(ah[rt], bh[ci], acc[rt][ci], 0, 0, 0);
                    acc[rt][ci] = __builtin_amdgcn_mfma_f32_16x16x32_f16(ah[rt], bl[ci], acc[rt][ci], 0, 0, 0);
                }
        }

#pragma unroll
        for (int rt = 0; rt < 4; ++rt)
#pragma unroll
            for (int rr = 0; rr < 4; ++rr) {
                int row = rt * 16 + quad * 4 + rr;
                int n = nodeBase + row;
                if (n < N_NODES) {
                    size_t b = (size_t)n * 640 + cp * 128 + w * 32;
                    Z[b + l15]      = f2b(acc[rt][0][rr]);
                    Z[b + 16 + l15] = f2b(acc[rt][1][rr]);
                }
            }
    }
}

// ---- finalize: out[n] = selfZ + sum_e s_e * Z[src_e, plane t_e] + bias (+norm/relu)
// 8 nodes per wave; perm64 window 64-deep; double-buffered 16-deep gather pipeline
// (issue batch b+1 before consuming batch b) so waves never sit on the L3 latency tail.
#define FLUSH_NODE() do {                                                     \
    int n_ = n0 + cur;                                                        \
    float vx_ = __uint_as_float(sv[0] << 16) + accx + bv.x;                   \
    float vy_ = __uint_as_float(sv[0] & 0xffff0000u) + accy + bv.y;           \
    if (doNormRelu) {                                                         \
        float s_ = vx_ * vx_ + vy_ * vy_;                                     \
        s_ += __shfl_xor(s_, 1);  s_ += __shfl_xor(s_, 2);                    \
        s_ += __shfl_xor(s_, 4);  s_ += __shfl_xor(s_, 8);                    \
        s_ += __shfl_xor(s_, 16); s_ += __shfl_xor(s_, 32);                   \
        float sc_ = 1.0f / fmaxf(sqrtf(s_), 1e-12f);                          \
        vx_ = fmaxf(vx_ * sc_, 0.f);                                          \
        vy_ = fmaxf(vy_ * sc_, 0.f);                                          \
        ((unsigned*)outH)[(size_t)n_ * 64 + lane] = pack2h(vx_, vy_);         \
    } else {                                                                  \
        ((float2*)outF)[(size_t)n_ * 64 + lane] = make_float2(vx_, vy_);      \
    }                                                                         \
    _Pragma("unroll")                                                         \
    for (int q_ = 0; q_ < 7; ++q_) sv[q_] = sv[q_ + 1];                       \
} while (0)

// advance the 64-entry perm window so batch starting at EN is fully inside
#define ADVW(EN) do {                                                         \
    if ((EN) - pbase >= 64) {                                                 \
        pbase += 64;                                                          \
        P0 = P1;                                                              \
        int i2_ = pbase + 64 + lane;                                          \
        i2_ = i2_ < N_EDGES - 1 ? i2_ : N_EDGES - 1;                          \
        P1 = P[i2_];                                                          \
    }                                                                         \
} while (0)

// issue 16-deep batch B_ into (UV, SC, NB)
#define ISSUE(B_, UV, SC, NB) do {                                            \
    int e_ = s0 + ((B_) << 4);                                                \
    int r_ = eend - e_;                                                       \
    NB = r_ > 16 ? 16 : (r_ > 0 ? r_ : 0);                                    \
    _Pragma("unroll")                                                         \
    for (int j_ = 0; j_ < 16; ++j_) {                                         \
        if (j_ < NB) {                                                        \
            int idx_ = e_ + j_ - pbase;                                       \
            unsigned ow_ = (unsigned)__builtin_amdgcn_readlane((int)P0.x, idx_); \
            SC[j_] = __uint_as_float((unsigned)__builtin_amdgcn_readlane((int)P0.y, idx_)); \
            UV[j_] = Z32[(size_t)ow_ + lane];                                 \
        }                                                                     \
    }                                                                         \
} while (0)

// consume batch B_ from (UV, SC, NB)
#define CONSUME(B_, UV, SC, NB) do {                                          \
    int e_ = s0 + ((B_) << 4);                                                \
    _Pragma("unroll")                                                         \
    for (int j_ = 0; j_ < 16; ++j_) {                                         \
        if (j_ < NB) {                                                        \
            int ge_ = e_ + j_;                                                \
            while (ge_ >= nextB) {                                            \
                FLUSH_NODE();                                                 \
                accx = 0.f; accy = 0.f;                                       \
                cur++;                                                        \
                nextB = __builtin_amdgcn_readlane(vb, cur + 1 < 8 ? cur + 1 : 8); \
            }                                                                 \
            accx = fmaf(__uint_as_float(UV[j_] << 16), SC[j_], accx);         \
            accy = fmaf(__uint_as_float(UV[j_] & 0xffff0000u), SC[j_], accy); \
        }                                                                     \
    }                                                                         \
} while (0)

__global__ __launch_bounds__(256) void finalize(
    const unsigned short* __restrict__ Z,
    const unsigned long long* __restrict__ perm64,
    const int* __restrict__ off,              // [N_SEG+1], sentinel = N_EDGES
    const float* __restrict__ bias,
    float* __restrict__ outF,                 // fp32 output (layer 2)
    unsigned short* __restrict__ outH,        // fp16 output (layer 1: norm+relu)
    int doNormRelu)
{
    const int lane = threadIdx.x & 63;
    const int w = threadIdx.x >> 6;
    const int n0 = (blockIdx.x * 4 + w) * 8;
    if (n0 >= N_NODES) return;

    const unsigned* Z32 = (const unsigned*)Z;
    const uint2* P = (const uint2*)perm64;

    // 9 node boundaries in a lane vector (node k start = off[(n0+k)*4])
    int bl = lane < 8 ? lane : 8;
    int vb = off[(n0 + bl) * 4];

    float2 bv = ((const float2*)bias)[lane];

    // prefetch self rows (plane 0) for the 8 nodes
    unsigned sv[8];
#pragma unroll
    for (int i = 0; i < 8; ++i)
        sv[i] = Z32[(size_t)(n0 + i) * 320 + lane];

    int s0   = __builtin_amdgcn_readfirstlane(vb);
    int eend = __builtin_amdgcn_readlane(vb, 8);

    int pbase = s0;
    int i0 = pbase + lane;          i0 = i0 < N_EDGES - 1 ? i0 : N_EDGES - 1;
    int i1 = pbase + 64 + lane;     i1 = i1 < N_EDGES - 1 ? i1 : N_EDGES - 1;
    uint2 P0 = P[i0];
    uint2 P1 = P[i1];

    int cur = 0;
    int nextB = __builtin_amdgcn_readlane(vb, 1);
    float accx = 0.f, accy = 0.f;

    int nBatch = (eend - s0 + 15) >> 4;

    if (nBatch > 0) {
        unsigned uvA[16], uvB[16];
        float scA[16], scB[16];
        int nbA, nbB;

        ISSUE(0, uvA, scA, nbA);

        int b = 0;
        while (true) {
            // even step: issue b+1 into B, consume b from A
            if (b + 1 < nBatch) {
                ADVW(s0 + ((b + 1) << 4));
                ISSUE(b + 1, uvB, scB, nbB);
            } else nbB = 0;
            CONSUME(b, uvA, scA, nbA);
            if (++b >= nBatch) break;

            // odd step: issue b+1 into A, consume b from B
            if (b + 1 < nBatch) {
                ADVW(s0 + ((b + 1) << 4));
                ISSUE(b + 1, uvA, scA, nbA);
            } else nbA = 0;
            CONSUME(b, uvB, scB, nbB);
            if (++b >= nBatch) break;
        }
    }

    while (cur < 8) {
        FLUSH_NODE();
        accx = 0.f; accy = 0.f;
        cur++;
    }
}

extern "C" void kernel_launch(void* const* d_in, const int* in_sizes, int n_in,
                              void* d_out, int out_size, void* d_ws, size_t ws_size,
                              hipStream_t stream)
{
    const float* x   = (const float*)d_in[0];
    const float* Ws1 = (const float*)d_in[1];
    const float* Wn1 = (const float*)d_in[2];
    const float* b1  = (const float*)d_in[3];
    const float* Ws2 = (const float*)d_in[4];
    const float* Wn2 = (const float*)d_in[5];
    const float* b2  = (const float*)d_in[6];
    const int* edge_index = (const int*)d_in[7];
    const int* edge_type  = (const int*)d_in[8];

    const int* srcA = edge_index;
    const int* dstA = edge_index + N_EDGES;

    // workspace layout (perm64 kept 8B-aligned)
    unsigned short* Z   = (unsigned short*)d_ws;             // N*640 u16 = 64 MB
    unsigned short* x16 = Z + (size_t)N_NODES * 640;         // N*128 u16
    unsigned short* h1  = x16 + (size_t)N_NODES * F;         // N*128 u16
    unsigned short* Wh  = h1 + (size_t)N_NODES * F;          // 2*WELEM u16
    unsigned short* Wl  = Wh + (size_t)2 * WELEM;            // 2*WELEM u16
    float* bavg = (float*)(Wl + (size_t)2 * WELEM);          // 256 f32
    int* counts = (int*)(bavg + 2 * F);                      // N_SEG+2 (off + sentinel + pad)
    int* cursor = counts + (N_SEG + 2);                      // N_SEG
    int* bsum   = cursor + N_SEG;                            // 256
    unsigned long long* perm64 = (unsigned long long*)(bsum + 256);  // N_EDGES u64
    int* off = counts;                                       // alias after csr_prep

    // ---- single cooperative kernel: prep + CSR ----
    {
        const float* x_ = x;
        const float* Ws1_ = Ws1; const float* Wn1_ = Wn1; const float* b1_ = b1;
        const float* Ws2_ = Ws2; const float* Wn2_ = Wn2; const float* b2_ = b2;
        const int* srcA_ = srcA; const int* dstA_ = dstA; const int* typA_ = edge_type;
        unsigned short* x16_ = x16;
        unsigned short* Wh_ = Wh; unsigned short* Wl_ = Wl;
        float* bavg_ = bavg;
        int* counts_ = counts; int* cursor_ = cursor; int* bsum_ = bsum;
        unsigned long long* perm64_ = perm64;
        void* args[] = {
            (void*)&x_,
            (void*)&Ws1_, (void*)&Wn1_, (void*)&b1_,
            (void*)&Ws2_, (void*)&Wn2_, (void*)&b2_,
            (void*)&srcA_, (void*)&dstA_, (void*)&typA_,
            (void*)&x16_, (void*)&Wh_, (void*)&Wl_, (void*)&bavg_,
            (void*)&counts_, (void*)&cursor_, (void*)&bsum_, (void*)&perm64_
        };
        hipLaunchCooperativeKernel((const void*)csr_prep, dim3(SCAN_BLK), dim3(256),
                                   args, 0, stream);
    }

    const int gemmGrid = (N_NODES + 63) / 64;     // 782
    const int finGrid  = (N_NODES + 31) / 32;     // 1563

    // ---------- layer 1 ----------
    hipLaunchKernelGGL(gemm_z, dim3(gemmGrid), dim3(256), 0, stream,
                       x16, Wh, Wl, Z);
    hipLaunchKernelGGL(finalize, dim3(finGrid), dim3(256), 0, stream,
                       Z, perm64, off, bavg, (float*)nullptr, h1, 1);

    // ---------- layer 2 ----------
    hipLaunchKernelGGL(gemm_z, dim3(gemmGrid), dim3(256), 0, stream,
                       h1, Wh + WELEM, Wl + WELEM, Z);
    hipLaunchKernelGGL(finalize, dim3(finGrid), dim3(256), 0, stream,
                       Z, perm64, off, bavg + F, (float*)d_out,
                       (unsigned short*)nullptr, 0);
}

// Round 5
// 290.871 us; speedup vs baseline: 1.4989x; 1.4989x over previous
//
#include <hip/hip_runtime.h>
#include <math.h>

#define N_NODES 50000
#define N_EDGES 600000
#define F 128
#define NT 4
#define NKTG 20                // K tiles of 32 (640 total K)
#define NCT 8                  // out-col tiles of 16 (128/16)
#define N_SEG (NT * N_NODES)   // 200000
#define SCAN_BLK 196           // ceil(N_SEG / 1024)
#define WELEM (NKTG * NCT * 64 * 8)  // 81920 fp16 elements per layer
#define PER_LAYER (NKTG * NCT * 64)  // 10240 weight fragments

typedef __attribute__((ext_vector_type(8))) _Float16 f16x8;
typedef __attribute__((ext_vector_type(4))) float f32x4;

__device__ __forceinline__ unsigned short f2h(float f) {
    _Float16 h = (_Float16)f;
    return __builtin_bit_cast(unsigned short, h);
}
__device__ __forceinline__ float h2f(unsigned short u) {
    return (float)__builtin_bit_cast(_Float16, u);
}
__device__ __forceinline__ unsigned pack2h(float a, float b) {
    return (unsigned)f2h(a) | ((unsigned)f2h(b) << 16);
}

// ---- build combined weights B[640,128] per layer, fp16 hi/lo, MFMA-frag order ----
// K rows 0..127 = 0.25*sum_t Ws[t] (self); rows 128+t*128.. = 0.25*Wn[t]
__global__ __launch_bounds__(256) void build_w(
    const float* __restrict__ Ws1, const float* __restrict__ Wn1, const float* __restrict__ b1,
    const float* __restrict__ Ws2, const float* __restrict__ Wn2, const float* __restrict__ b2,
    unsigned short* __restrict__ Wh, unsigned short* __restrict__ Wl,
    float* __restrict__ bavg)
{
    int idx = blockIdx.x * 256 + threadIdx.x;
    if (idx < 2 * PER_LAYER) {
        int l = idx >= PER_LAYER;
        int rem = idx - l * PER_LAYER;
        int lane = rem & 63;
        int ct = (rem >> 6) & 7;
        int ktg = (rem >> 6) >> 3;
        const float* Wsl = l ? Ws2 : Ws1;
        const float* Wnl = l ? Wn2 : Wn1;
        unsigned short* oh = Wh + (size_t)l * WELEM + (size_t)rem * 8;
        unsigned short* ol = Wl + (size_t)l * WELEM + (size_t)rem * 8;
        int c = ct * 16 + (lane & 15);
        int kb = ktg * 32 + (lane >> 4) * 8;
#pragma unroll
        for (int j = 0; j < 8; ++j) {
            int k = kb + j;
            float v;
            if (k < F) {
                v = 0.25f * (Wsl[(0 * F + k) * F + c] + Wsl[(1 * F + k) * F + c] +
                             Wsl[(2 * F + k) * F + c] + Wsl[(3 * F + k) * F + c]);
            } else {
                int t = (k - F) >> 7;
                int kk = (k - F) & (F - 1);
                v = 0.25f * Wnl[((size_t)t * F + kk) * F + c];
            }
            _Float16 hh = (_Float16)v;
            oh[j] = __builtin_bit_cast(unsigned short, hh);
            ol[j] = f2h(v - (float)hh);
        }
    } else {
        int k = idx - 2 * PER_LAYER;
        if (k < 2 * F) {
            int l = k >> 7;
            int j = k & (F - 1);
            const float* bl = l ? b2 : b1;
            bavg[k] = 0.25f * (bl[j] + bl[F + j] + bl[2 * F + j] + bl[3 * F + j]);
        }
    }
}

// ---- cast x fp32 -> fp16 ----
__global__ __launch_bounds__(256) void cast_x(
    const float* __restrict__ x, unsigned short* __restrict__ x16)
{
    int i = blockIdx.x * 256 + threadIdx.x;
    if (i < N_NODES * 64) {
        float2 v = ((const float2*)x)[i];
        ((unsigned*)x16)[i] = pack2h(v.x, v.y);
    }
}

// ---------------- CSR build: seg = dst*4 + t ----------------
__global__ __launch_bounds__(256) void hist_kernel(
    const int* __restrict__ dstA, const int* __restrict__ typA, int* __restrict__ counts)
{
    int e = blockIdx.x * 256 + threadIdx.x;
    if (e < N_EDGES) atomicAdd(&counts[dstA[e] * NT + typA[e]], 1);
}

__global__ __launch_bounds__(256) void scan1(int* __restrict__ counts, int* __restrict__ bsum)
{
    __shared__ int sh[256];
    int t = threadIdx.x;
    int base = blockIdx.x * 1024 + t * 4;
    int v[4];
    int tot = 0;
#pragma unroll
    for (int j = 0; j < 4; ++j) {
        int i = base + j;
        v[j] = (i < N_SEG) ? counts[i] : 0;
        tot += v[j];
    }
    sh[t] = tot;
    __syncthreads();
    for (int ofs = 1; ofs < 256; ofs <<= 1) {
        int add = (t >= ofs) ? sh[t - ofs] : 0;
        __syncthreads();
        sh[t] += add;
        __syncthreads();
    }
    int excl = (t > 0) ? sh[t - 1] : 0;
    if (t == 255) bsum[blockIdx.x] = sh[255];
#pragma unroll
    for (int j = 0; j < 4; ++j) {
        int i = base + j;
        if (i < N_SEG) counts[i] = excl;
        excl += v[j];
    }
}

__global__ __launch_bounds__(256) void scan2(int* __restrict__ bsum)
{
    __shared__ int sh[256];
    int t = threadIdx.x;
    sh[t] = (t < SCAN_BLK) ? bsum[t] : 0;
    __syncthreads();
    for (int ofs = 1; ofs < 256; ofs <<= 1) {
        int add = (t >= ofs) ? sh[t - ofs] : 0;
        __syncthreads();
        sh[t] += add;
        __syncthreads();
    }
    int excl = (t > 0) ? sh[t - 1] : 0;
    if (t < SCAN_BLK) bsum[t] = excl;
}

// finalize offsets in place; pad [N_SEG, N_SEG+128] with N_EDGES so the fused
// kernel's per-wave 33-boundary loads past the last node read empty segments
__global__ __launch_bounds__(256) void scan3(
    int* __restrict__ counts, const int* __restrict__ bsum, int* __restrict__ cursor)
{
    int i = blockIdx.x * 256 + threadIdx.x;
    if (i < N_SEG) {
        int v = counts[i] + bsum[i >> 10];
        counts[i] = v;
        cursor[i] = v;
    } else if (i <= N_SEG + 128) {
        counts[i] = N_EDGES;
    }
}

// permute: bucket-sorted edges; payload = (fp32 scale bits << 32) | H-row dword offset
__global__ __launch_bounds__(256) void permute_kernel(
    const int* __restrict__ srcA, const int* __restrict__ dstA, const int* __restrict__ typA,
    const int* __restrict__ off, int* __restrict__ cursor,
    unsigned long long* __restrict__ perm64)
{
    int e = blockIdx.x * 256 + threadIdx.x;
    if (e < N_EDGES) {
        int t = typA[e];
        int seg = dstA[e] * NT + t;
        int pos = atomicAdd(&cursor[seg], 1);
        float inv = 1.0f / fmaxf((float)(off[seg + 1] - off[seg]), 1.0f);
        unsigned offw = (unsigned)(srcA[e] * 64);     // dword offset into H (fp16 row)
        perm64[pos] = ((unsigned long long)__float_as_uint(inv) << 32) | offw;
    }
}

// ================== fused layer ==================
// out[N,128] = [H | mean_t(H[src])][N,640] @ B[640,128] + bias (+norm/relu)
// Block = 32 nodes, 4 waves (8 nodes/wave). Phase 1: stage H-self to LDS +
// chain-free double-buffered gather of per-(node,type) means into LDS A-tile.
// One barrier. Phase 2: 20-K-tile MFMA GEMM from LDS + fused epilogue.

// flush current segment's mean (pre-scaled accumulate) into the LDS Agg tile
#define FLUSH_SEG() do {                                                      \
    AGd[(w << 3) + (cur >> 2)][((cur & 3) << 6) + lane] = pack2h(accx, accy); \
    accx = 0.f; accy = 0.f;                                                   \
    cur++;                                                                    \
    nextB = __builtin_amdgcn_readlane(vb, cur + 1 < 32 ? cur + 1 : 32);       \
} while (0)

// advance the 64-entry perm window so the batch starting at EN is fully inside
#define ADVW(EN) do {                                                         \
    if ((EN) - pbase >= 64) {                                                 \
        pbase += 64;                                                          \
        P0 = P1;                                                              \
        int i2_ = pbase + 64 + lane;                                          \
        i2_ = i2_ < N_EDGES - 1 ? i2_ : N_EDGES - 1;                          \
        P1 = P[i2_];                                                          \
    }                                                                         \
} while (0)

// issue 16-deep batch B_ into (UV, SC, NB)
#define ISSUE(B_, UV, SC, NB) do {                                            \
    int e_ = s0 + ((B_) << 4);                                                \
    int r_ = eend - e_;                                                       \
    NB = r_ > 16 ? 16 : (r_ > 0 ? r_ : 0);                                    \
    _Pragma("unroll")                                                         \
    for (int j_ = 0; j_ < 16; ++j_) {                                         \
        if (j_ < NB) {                                                        \
            int idx_ = e_ + j_ - pbase;                                       \
            unsigned ow_ = (unsigned)__builtin_amdgcn_readlane((int)P0.x, idx_); \
            SC[j_] = __uint_as_float((unsigned)__builtin_amdgcn_readlane((int)P0.y, idx_)); \
            UV[j_] = H32[(size_t)ow_ + lane];                                 \
        }                                                                     \
    }                                                                         \
} while (0)

// consume batch B_ (flush at segment boundaries)
#define CONSUME(B_, UV, SC, NB) do {                                          \
    int e_ = s0 + ((B_) << 4);                                                \
    _Pragma("unroll")                                                         \
    for (int j_ = 0; j_ < 16; ++j_) {                                         \
        if (j_ < NB) {                                                        \
            int ge_ = e_ + j_;                                                \
            while (ge_ >= nextB) { FLUSH_SEG(); }                             \
            accx = fmaf(h2f((unsigned short)(UV[j_] & 0xffffu)), SC[j_], accx); \
            accy = fmaf(h2f((unsigned short)(UV[j_] >> 16)), SC[j_], accy);   \
        }                                                                     \
    }                                                                         \
} while (0)

__global__ __launch_bounds__(256) void fused_layer(
    const unsigned short* __restrict__ Hin,   // [N,128] fp16 (self + gather source)
    const unsigned long long* __restrict__ perm64,
    const int* __restrict__ off,              // [N_SEG+129], tail = N_EDGES
    const unsigned short* __restrict__ Wh,    // frag-ordered fp16 hi (this layer)
    const unsigned short* __restrict__ Wl,    // frag-ordered fp16 lo
    const float* __restrict__ bias,           // 128 fp32
    float* __restrict__ outF,                 // fp32 output (layer 2)
    unsigned short* __restrict__ outH,        // fp16 output (layer 1: norm+relu)
    int doNormRelu)
{
    __shared__ unsigned short HS[32][136];    // H-self tile (K chunk 0), padded
    __shared__ unsigned AGd[32][261];         // Agg tile [32 nodes][512 halves], dword view
    __shared__ float rs[32][4];               // row sumsq partials (L1 epilogue)

    const int tid = threadIdx.x;
    const int lane = tid & 63;
    const int w = tid >> 6;
    const int quad = lane >> 4;
    const int l15 = lane & 15;
    const int nodeBase = blockIdx.x * 32;

    // ---- stage H-self tile (coalesced) ----
    {
        int r = tid >> 3;
        int cb = (tid & 7) * 16;
        int n = nodeBase + r;
        int nc = n < N_NODES ? n : N_NODES - 1;
        const unsigned short* sp = Hin + (size_t)nc * F + cb;
        *(uint4*)&HS[r][cb]     = *(const uint4*)sp;
        *(uint4*)&HS[r][cb + 8] = *(const uint4*)(sp + 8);
    }

    // ---- gather phase: per-wave 8 nodes = 32 (node,type) segments ----
    const unsigned* H32 = (const unsigned*)Hin;
    const uint2* P = (const uint2*)perm64;
    const int n0 = nodeBase + w * 8;

    int bl = lane < 32 ? lane : 32;
    int vb = off[n0 * 4 + bl];                // 33 segment boundaries

    int s0   = __builtin_amdgcn_readfirstlane(vb);
    int eend = __builtin_amdgcn_readlane(vb, 32);

    int pbase = s0;
    int i0 = pbase + lane;          i0 = i0 < N_EDGES - 1 ? i0 : N_EDGES - 1;
    int i1 = pbase + 64 + lane;     i1 = i1 < N_EDGES - 1 ? i1 : N_EDGES - 1;
    uint2 P0 = P[i0];
    uint2 P1 = P[i1];

    int cur = 0;
    int nextB = __builtin_amdgcn_readlane(vb, 1);
    float accx = 0.f, accy = 0.f;

    int nBatch = (eend - s0 + 15) >> 4;
    if (nBatch > 0) {
        unsigned uvA[16], uvB[16];
        float scA[16], scB[16];
        int nbA, nbB;

        ISSUE(0, uvA, scA, nbA);

        int b = 0;
        while (true) {
            if (b + 1 < nBatch) {
                ADVW(s0 + ((b + 1) << 4));
                ISSUE(b + 1, uvB, scB, nbB);
            } else nbB = 0;
            CONSUME(b, uvA, scA, nbA);
            if (++b >= nBatch) break;

            if (b + 1 < nBatch) {
                ADVW(s0 + ((b + 1) << 4));
                ISSUE(b + 1, uvA, scA, nbA);
            } else nbA = 0;
            CONSUME(b, uvB, scB, nbB);
            if (++b >= nBatch) break;
        }
    }
    while (cur < 32) { FLUSH_SEG(); }         // flush trailing empty segments

    __syncthreads();                          // Agg + H-self staged

    // ---- GEMM phase: [32,640] @ [640,128] from LDS ----
    f32x4 acc[2][2];
#pragma unroll
    for (int rt = 0; rt < 2; ++rt)
#pragma unroll
        for (int ci = 0; ci < 2; ++ci)
            acc[rt][ci] = (f32x4){0.f, 0.f, 0.f, 0.f};

    const f16x8* BH = (const f16x8*)Wh;
    const f16x8* BL = (const f16x8*)Wl;

#pragma unroll 4
    for (int ktg = 0; ktg < NKTG; ++ktg) {
        f16x8 bh[2], blo[2];
#pragma unroll
        for (int ci = 0; ci < 2; ++ci) {
            int fi = (ktg * NCT + (w * 2 + ci)) * 64 + lane;
            bh[ci]  = BH[fi];
            blo[ci] = BL[fi];
        }
        f16x8 ah[2];
        if (ktg < 4) {
#pragma unroll
            for (int rt = 0; rt < 2; ++rt)
                ah[rt] = *(const f16x8*)&HS[rt * 16 + l15][ktg * 32 + quad * 8];
        } else {
#pragma unroll
            for (int rt = 0; rt < 2; ++rt) {
                int row = rt * 16 + l15;
                int cd = ((ktg - 4) << 4) + (quad << 2);
                uint4 t4;
                t4.x = AGd[row][cd];
                t4.y = AGd[row][cd + 1];
                t4.z = AGd[row][cd + 2];
                t4.w = AGd[row][cd + 3];
                ah[rt] = __builtin_bit_cast(f16x8, t4);
            }
        }
#pragma unroll
        for (int rt = 0; rt < 2; ++rt)
#pragma unroll
            for (int ci = 0; ci < 2; ++ci) {
                acc[rt][ci] = __builtin_amdgcn_mfma_f32_16x16x32_f16(ah[rt], bh[ci],  acc[rt][ci], 0, 0, 0);
                acc[rt][ci] = __builtin_amdgcn_mfma_f32_16x16x32_f16(ah[rt], blo[ci], acc[rt][ci], 0, 0, 0);
            }
    }

    // ---- epilogue ----
    float bv0 = bias[w * 32 + l15];
    float bv1 = bias[w * 32 + 16 + l15];

    if (doNormRelu) {
#pragma unroll
        for (int rt = 0; rt < 2; ++rt)
#pragma unroll
            for (int rr = 0; rr < 4; ++rr) {
                float vx = acc[rt][0][rr] + bv0;
                float vy = acc[rt][1][rr] + bv1;
                float s = vx * vx + vy * vy;
                s += __shfl_xor(s, 1);
                s += __shfl_xor(s, 2);
                s += __shfl_xor(s, 4);
                s += __shfl_xor(s, 8);
                if (l15 == 0) rs[rt * 16 + quad * 4 + rr][w] = s;
            }
        __syncthreads();
#pragma unroll
        for (int rt = 0; rt < 2; ++rt)
#pragma unroll
            for (int rr = 0; rr < 4; ++rr) {
                int row = rt * 16 + quad * 4 + rr;
                int nn = nodeBase + row;
                if (nn < N_NODES) {
                    float tot = rs[row][0] + rs[row][1] + rs[row][2] + rs[row][3];
                    float sc = 1.0f / fmaxf(sqrtf(tot), 1e-12f);
                    float vx = fmaxf((acc[rt][0][rr] + bv0) * sc, 0.f);
                    float vy = fmaxf((acc[rt][1][rr] + bv1) * sc, 0.f);
                    outH[(size_t)nn * F + w * 32 + l15]      = f2h(vx);
                    outH[(size_t)nn * F + w * 32 + 16 + l15] = f2h(vy);
                }
            }
    } else {
#pragma unroll
        for (int rt = 0; rt < 2; ++rt)
#pragma unroll
            for (int rr = 0; rr < 4; ++rr) {
                int nn = nodeBase + rt * 16 + quad * 4 + rr;
                if (nn < N_NODES) {
                    float* o = outF + (size_t)nn * F + w * 32 + l15;
                    o[0]  = acc[rt][0][rr] + bv0;
                    o[16] = acc[rt][1][rr] + bv1;
                }
            }
    }
}

extern "C" void kernel_launch(void* const* d_in, const int* in_sizes, int n_in,
                              void* d_out, int out_size, void* d_ws, size_t ws_size,
                              hipStream_t stream)
{
    const float* x   = (const float*)d_in[0];
    const float* Ws1 = (const float*)d_in[1];
    const float* Wn1 = (const float*)d_in[2];
    const float* b1  = (const float*)d_in[3];
    const float* Ws2 = (const float*)d_in[4];
    const float* Wn2 = (const float*)d_in[5];
    const float* b2  = (const float*)d_in[6];
    const int* edge_index = (const int*)d_in[7];
    const int* edge_type  = (const int*)d_in[8];

    const int* srcA = edge_index;
    const int* dstA = edge_index + N_EDGES;

    // workspace layout (perm64 kept 8B-aligned)
    unsigned short* x16 = (unsigned short*)d_ws;             // N*128 u16 = 12.8 MB
    unsigned short* h1  = x16 + (size_t)N_NODES * F;         // N*128 u16
    unsigned short* Wh  = h1 + (size_t)N_NODES * F;          // 2*WELEM u16
    unsigned short* Wl  = Wh + (size_t)2 * WELEM;            // 2*WELEM u16
    float* bavg = (float*)(Wl + (size_t)2 * WELEM);          // 256 f32
    int* counts = (int*)(bavg + 2 * F);                      // N_SEG + 160 (off + pad)
    int* cursor = counts + (N_SEG + 160);                    // N_SEG
    int* bsum   = cursor + N_SEG;                            // 256
    unsigned long long* perm64 = (unsigned long long*)(bsum + 256);  // N_EDGES u64
    int* off = counts;                                       // alias after scan3

    // weights + bias + fp16 cast of x
    hipLaunchKernelGGL(build_w, dim3(81), dim3(256), 0, stream,
                       Ws1, Wn1, b1, Ws2, Wn2, b2, Wh, Wl, bavg);
    hipLaunchKernelGGL(cast_x, dim3((N_NODES * 64 + 255) / 256), dim3(256), 0, stream,
                       x, x16);

    // CSR build (shared by both layers)
    hipMemsetAsync(counts, 0, (size_t)N_SEG * sizeof(int), stream);
    hipLaunchKernelGGL(hist_kernel, dim3((N_EDGES + 255) / 256), dim3(256), 0, stream,
                       dstA, edge_type, counts);
    hipLaunchKernelGGL(scan1, dim3(SCAN_BLK), dim3(256), 0, stream, counts, bsum);
    hipLaunchKernelGGL(scan2, dim3(1), dim3(256), 0, stream, bsum);
    hipLaunchKernelGGL(scan3, dim3((N_SEG + 129 + 255) / 256), dim3(256), 0, stream,
                       counts, bsum, cursor);
    hipLaunchKernelGGL(permute_kernel, dim3((N_EDGES + 255) / 256), dim3(256), 0, stream,
                       srcA, dstA, edge_type, off, cursor, perm64);

    const int fusedGrid = (N_NODES + 31) / 32;    // 1563

    // ---------- layer 1 ----------
    hipLaunchKernelGGL(fused_layer, dim3(fusedGrid), dim3(256), 0, stream,
                       x16, perm64, off, Wh, Wl, bavg,
                       (float*)nullptr, h1, 1);

    // ---------- layer 2 ----------
    hipLaunchKernelGGL(fused_layer, dim3(fusedGrid), dim3(256), 0, stream,
                       h1, perm64, off, Wh + WELEM, Wl + WELEM, bavg + F,
                       (float*)d_out, (unsigned short*)nullptr, 0);
}